// Round 6
// baseline (149.907 us; speedup 1.0000x reference)
//
#include <hip/hip_runtime.h>

// IDMForwardSim, 2-kernel structure with async-staged fusion:
//  1) precompute_pack: Wc = W1@W2 packed as bf16 hi/lo MFMA B-fragments (ws)
//  2) fused_k (320 thr, 32 rows/block):
//     waves 2-4: issue us-chunk (35.8KB) + prm via global_load_lds  (T14)
//     waves 0-1: x loads -> trunc hi/lo bf16 split -> MFMA -> sigmoid -> satt
//     barrier (drains vmcnt) -> all 320: att write + IDM epilogue from LDS.
//     us stream overlaps matvec compute; att never round-trips HBM.

#define TT 40
#define DD 128
#define ACT_CLIP 3.5f
#define ATT_TEMP 5.0f

typedef short short8 __attribute__((ext_vector_type(8)));
typedef float f32x4 __attribute__((ext_vector_type(4)));

__device__ __forceinline__ unsigned int bf16_rne(float v) {
    unsigned int u = __float_as_uint(v);
    return (u + 0x7FFFu + ((u >> 16) & 1u)) >> 16;
}

__device__ __forceinline__ void gld16(const void* g, void* l) {
    __builtin_amdgcn_global_load_lds(
        (const __attribute__((address_space(1))) unsigned int*)g,
        (__attribute__((address_space(3))) unsigned int*)l, 16, 0, 0);
}

// ---------------------------------------------------------------------------
// Kernel 1: pack Wc (128x48, zero-padded cols 40..47) as MFMA B-fragments.
// Record (s,n,h): s=k-step(0..3), n=n-tile(0..2), h=0 hi/1 lo. 64 lanes x 16B.
// Element j of lane l: k = s*32 + (l>>4)*8 + j ; col = n*16 + (l&15).
// ---------------------------------------------------------------------------
__global__ __launch_bounds__(256) void precompute_pack(
    const float* __restrict__ W1, const float* __restrict__ b1,
    const float* __restrict__ W2, const float* __restrict__ b2,
    unsigned int* __restrict__ wpack,   // 1536 * 16B records
    float* __restrict__ bcp)            // 48 floats
{
    int idx = blockIdx.x * 256 + threadIdx.x;
    if (idx < 1536) {
        int l   = idx & 63;
        int rec = idx >> 6;           // ((s*3+n)*2+h)
        int h   = rec & 1;
        int sn  = rec >> 1;           // s*3+n
        int n   = sn % 3, s = sn / 3;
        int col = n * 16 + (l & 15);
        int k0  = s * 32 + (l >> 4) * 8;
        unsigned short hv[8];
#pragma unroll
        for (int j = 0; j < 8; ++j) {
            float v = 0.0f;
            if (col < TT) {
                int k = k0 + j;
                for (int m = 0; m < 100; ++m)
                    v = fmaf(W1[k * 100 + m], W2[m * TT + col], v);
            }
            unsigned int hi = bf16_rne(v);
            float hif = __uint_as_float(hi << 16);
            unsigned int lo = bf16_rne(v - hif);
            hv[j] = (unsigned short)(h == 0 ? hi : lo);
        }
        uint4 o;
        o.x = hv[0] | ((unsigned)hv[1] << 16);
        o.y = hv[2] | ((unsigned)hv[3] << 16);
        o.z = hv[4] | ((unsigned)hv[5] << 16);
        o.w = hv[6] | ((unsigned)hv[7] << 16);
        reinterpret_cast<uint4*>(wpack)[idx] = o;
    } else if (idx < 1536 + 48) {
        int t = idx - 1536;
        float v = 0.0f;
        if (t < TT) {
            v = b2[t];
            for (int m = 0; m < 100; ++m)
                v = fmaf(b1[m], W2[m * TT + t], v);
        }
        bcp[t] = v;
    }
}

// ---------------------------------------------------------------------------
// Kernel 2: fused, async-staged. Block 320 = 5 waves, 32 rows/block.
// ---------------------------------------------------------------------------
__global__ __launch_bounds__(320, 3) void fused_k(
    const float* __restrict__ x,
    const unsigned int* __restrict__ wpack,
    const float* __restrict__ bcp,
    const float* __restrict__ us,
    const float* __restrict__ prm,
    float* __restrict__ act,             // = d_out
    float* __restrict__ attout)          // = d_out + B*TT
{
    __shared__ float sus[32 * 280];      // 35840 B (linear, gload_lds dest)
    __shared__ float satt[32 * TT];      // 5120 B
    __shared__ float sprm[256];          // 1024 B (160 used)

    int tid = threadIdx.x;
    int wave = tid >> 6, lane = tid & 63;
    size_t blk = blockIdx.x;

    if (wave >= 2) {
        // ---- issue the whole us chunk as direct-to-LDS DMA ------------
        int w = wave - 2;
        const float* usrc = us + blk * 8960;     // 32 rows * 280 floats
#pragma unroll
        for (int i = 0; i < 12; ++i) {
            int j = w * 12 + i;                  // waves: 0-11, 12-23, 24-34
            if (j < 35)
                gld16(usrc + j * 256 + lane * 4, &sus[j * 256]);
        }
        if (w == 2 && lane < 40)                 // prm: 32 rows x 5 = 640 B
            gld16(prm + blk * 160 + lane * 4, sprm);
    } else {
        // ---- matvec: rows blk*32 + wave*16 + l15 ----------------------
        int l15 = lane & 15, lk = lane >> 4;
        size_t row0 = blk * 32 + wave * 16 + l15;
        const float* xr = x + row0 * DD;

        float4 xv[8];
#pragma unroll
        for (int s = 0; s < 4; ++s) {
            xv[2 * s]     = *reinterpret_cast<const float4*>(xr + s * 32 + lk * 8);
            xv[2 * s + 1] = *reinterpret_cast<const float4*>(xr + s * 32 + lk * 8 + 4);
        }

        f32x4 acc[3] = {f32x4{0,0,0,0}, f32x4{0,0,0,0}, f32x4{0,0,0,0}};

#pragma unroll
        for (int s = 0; s < 4; ++s) {
            float fs[8] = {xv[2*s].x, xv[2*s].y, xv[2*s].z, xv[2*s].w,
                           xv[2*s+1].x, xv[2*s+1].y, xv[2*s+1].z, xv[2*s+1].w};
            union { unsigned int u[4]; short8 v; } ah, al;
#pragma unroll
            for (int p = 0; p < 4; ++p) {
                // truncation split: hi = chop16(x); lo = chop16(x - hi).
                // lo captures hi's residual exactly to 2^-16 rel; the
                // al*bh MFMA term corrects, so no RNE needed (saves VALU).
                unsigned int u0 = __float_as_uint(fs[2*p]);
                unsigned int u1 = __float_as_uint(fs[2*p+1]);
                ah.u[p] = (u0 >> 16) | (u1 & 0xFFFF0000u);
                float r0 = fs[2*p]   - __uint_as_float(u0 & 0xFFFF0000u);
                float r1 = fs[2*p+1] - __uint_as_float(u1 & 0xFFFF0000u);
                al.u[p] = (__float_as_uint(r0) >> 16) |
                          (__float_as_uint(r1) & 0xFFFF0000u);
            }
#pragma unroll
            for (int n = 0; n < 3; ++n) {
                int base = (s * 3 + n) * 512;   // uints: 2 records x 256
                short8 bh = *reinterpret_cast<const short8*>(&wpack[base + lane * 4]);
                short8 bl = *reinterpret_cast<const short8*>(&wpack[base + 256 + lane * 4]);
                acc[n] = __builtin_amdgcn_mfma_f32_16x16x32_bf16(ah.v, bh, acc[n], 0, 0, 0);
                acc[n] = __builtin_amdgcn_mfma_f32_16x16x32_bf16(al.v, bh, acc[n], 0, 0, 0);
                acc[n] = __builtin_amdgcn_mfma_f32_16x16x32_bf16(ah.v, bl, acc[n], 0, 0, 0);
            }
        }

        // C/D: col = l15 (+16*n), row = wave*16 + lk*4 + reg
#pragma unroll
        for (int n = 0; n < 3; ++n) {
            int col = n * 16 + l15;
            if (col < TT) {
                float bias = bcp[col];
#pragma unroll
                for (int r = 0; r < 4; ++r) {
                    int rowl = wave * 16 + lk * 4 + r;
                    float L = acc[n][r] + bias;
                    satt[rowl * TT + col] =
                        __builtin_amdgcn_rcpf(1.0f + __expf(-ATT_TEMP * L));
                }
            }
        }
    }
    __syncthreads();   // drains vmcnt (gload_lds) + lgkm; satt/sus/sprm ready

    // ---- att output write (mandatory), coalesced from LDS ------------
    float4 a4 = reinterpret_cast<const float4*>(satt)[tid];
    reinterpret_cast<float4*>(attout)[blk * 320u + tid] = a4;
    float av[4] = {a4.x, a4.y, a4.z, a4.w};

    // ---- IDM epilogue: item = tid = (row=tid/10, tg=tid%10) ----------
    unsigned int row_l = (unsigned)tid / 10u;

    const float4* fv = reinterpret_cast<const float4*>(sus + tid * 28);
    float f[28];
#pragma unroll
    for (int q = 0; q < 7; ++q) {
        float4 v = fv[q];
        f[q * 4 + 0] = v.x; f[q * 4 + 1] = v.y;
        f[q * 4 + 2] = v.z; f[q * 4 + 3] = v.w;
    }

    const float* pr = &sprm[row_l * 5];
    float desired_v    = pr[0];
    float desired_tgap = pr[1];
    float min_jamx     = pr[2];
    float max_act      = pr[3];
    float min_act      = pr[4];
    float inv_dv = __builtin_amdgcn_rcpf(desired_v);
    float coef   = 0.5f / sqrtf(max_act * min_act);

    float ares[4];
#pragma unroll
    for (int tt = 0; tt < 4; ++tt) {
        float vel = f[tt * 7 + 0];
        float dvl = f[tt * 7 + 2], dxl = f[tt * 7 + 3];
        float dvm = f[tt * 7 + 5], dxm = f[tt * 7 + 6];

        float r  = vel * inv_dv;
        float r2 = r * r;
        float common = 1.0f - r2 * r2;
        float base = fmaf(desired_tgap, vel, min_jamx);
        float gl = fmaf(vel * dvl, coef, base);
        float gm = fmaf(vel * dvm, coef, base);
        float ql = gl * __builtin_amdgcn_rcpf(dxl);
        float qm = gm * __builtin_amdgcn_rcpf(dxm);
        float al = max_act * (common - ql * ql);
        float am = max_act * (common - qm * qm);
        al = fminf(fmaxf(al, -ACT_CLIP), ACT_CLIP);
        am = fminf(fmaxf(am, -ACT_CLIP), ACT_CLIP);
        ares[tt] = fmaf(av[tt], al - am, am);
    }
    reinterpret_cast<float4*>(act)[blk * 320u + tid] =
        make_float4(ares[0], ares[1], ares[2], ares[3]);
}

extern "C" void kernel_launch(void* const* d_in, const int* in_sizes, int n_in,
                              void* d_out, int out_size, void* d_ws, size_t ws_size,
                              hipStream_t stream) {
    const float* us  = (const float*)d_in[0];
    const float* prm = (const float*)d_in[1];
    const float* x   = (const float*)d_in[2];
    const float* W1  = (const float*)d_in[3];
    const float* b1  = (const float*)d_in[4];
    const float* W2  = (const float*)d_in[5];
    const float* b2  = (const float*)d_in[6];
    float* out = (float*)d_out;

    int B = in_sizes[1] / 5;                 // 262144

    unsigned int* wpack = (unsigned int*)d_ws;          // 24576 B
    float* bcp = (float*)((char*)d_ws + 24576);         // 192 B

    float* attout = out + (size_t)B * TT;    // att half of d_out

    hipLaunchKernelGGL(precompute_pack, dim3(7), dim3(256), 0, stream,
                       W1, b1, W2, b2, wpack, bcp);
    hipLaunchKernelGGL(fused_k, dim3(B / 32), dim3(320), 0, stream,
                       x, wpack, bcp, us, prm, out, attout);
}